// Round 2
// baseline (297.324 us; speedup 1.0000x reference)
//
#include <hip/hip_runtime.h>
#include <math.h>

#define NN 200
#define ETOT 39800

__device__ __forceinline__ float sigf(float x) { return 1.0f / (1.0f + expf(-x)); }

// ---------------- zero-init ----------------
__global__ void k_zero(float* __restrict__ p, int n) {
  int i = blockIdx.x * blockDim.x + threadIdx.x;
  if (i < n) p[i] = 0.0f;
}

// ---------------- wp2 [128,4096] -> Wr [1024,512], Wr[i][k*4+o] = wp2[k][i*4+o] ----------------
__global__ void k_shuffle(const float* __restrict__ wp2, float* __restrict__ Wr) {
  int idx = blockIdx.x * 256 + threadIdx.x;      // 524288 total
  int i = idx >> 9, rem = idx & 511;
  int k = rem >> 2, o = rem & 3;
  Wr[idx] = wp2[k * 4096 + i * 4 + o];
}

// ---------------- P/Q: node_attr @ we1 halves (be1 folded into P) ----------------
__global__ __launch_bounds__(256) void k_PQ(const float* __restrict__ bbox, const float* __restrict__ dir,
                                            const float* __restrict__ we1, const float* __restrict__ be1,
                                            float* __restrict__ P, float* __restrict__ Q) {
  int n = blockIdx.x, c = threadIdx.x;
  float a[8];
#pragma unroll
  for (int r = 0; r < 4; ++r) a[r] = bbox[n * 4 + r] * (1.0f / 1024.0f);
#pragma unroll
  for (int r = 0; r < 4; ++r) a[4 + r] = dir[n * 4 + r];
  float p = be1[c], q = 0.0f;
#pragma unroll
  for (int r = 0; r < 8; ++r) {
    p += a[r] * we1[r * 256 + c];
    q += a[r] * we1[(8 + r) * 256 + c];
  }
  P[n * 256 + c] = p;
  Q[n * 256 + c] = q;
}

// ---------------- K-split tiled GEMM, atomicAdd partials into pre-zeroed C ----------------
// AMODE: 0 = A plain; 1 = A + bias + relu; 2 = A + bias
template <int AMODE>
__global__ __launch_bounds__(256) void gemm_ks(const float* __restrict__ A, const float* __restrict__ Abias,
                                               const float* __restrict__ Bp, float* __restrict__ C,
                                               int M, int N, int K, int KC) {
  __shared__ float As[64][33];
  __shared__ float Bs[32][64];
  const int m0 = blockIdx.x * 64, n0 = blockIdx.y * 64, k0 = blockIdx.z * KC;
  const int tid = threadIdx.x, tx = tid & 15, ty = tid >> 4;
  float acc[4][4] = {};

  for (int kk = k0; kk < k0 + KC; kk += 32) {
#pragma unroll
    for (int i = 0; i < 8; ++i) {
      int e = tid + i * 256;
      int r = e >> 5, c = e & 31;
      int m = m0 + r, k = kk + c;
      float v = 0.0f;
      if (m < M) {
        v = A[(size_t)m * K + k];
        if (AMODE != 0) {
          v += Abias[k];
          if (AMODE == 1) v = fmaxf(v, 0.0f);
        }
      }
      As[r][c] = v;
    }
#pragma unroll
    for (int i = 0; i < 8; ++i) {
      int e = tid + i * 256;
      int r = e >> 6, c = e & 63;
      Bs[r][c] = Bp[(size_t)(kk + r) * N + n0 + c];
    }
    __syncthreads();
#pragma unroll
    for (int k = 0; k < 32; ++k) {
      float a[4];
#pragma unroll
      for (int i = 0; i < 4; ++i) a[i] = As[ty * 4 + i][k];
      const float4 b4 = *(const float4*)&Bs[k][tx * 4];
      const float b[4] = {b4.x, b4.y, b4.z, b4.w};
#pragma unroll
      for (int i = 0; i < 4; ++i)
#pragma unroll
        for (int j = 0; j < 4; ++j) acc[i][j] += a[i] * b[j];
    }
    __syncthreads();
  }
#pragma unroll
  for (int i = 0; i < 4; ++i) {
    int m = m0 + ty * 4 + i;
    if (m < M) {
#pragma unroll
      for (int j = 0; j < 4; ++j) atomicAdd(&C[(size_t)m * N + n0 + tx * 4 + j], acc[i][j]);
    }
  }
}

// ---------------- per-node vectors: nce (output 1), U, agg init = x@root_w + root_b ----------------
__global__ __launch_bounds__(256) void k_nodevec(const float* __restrict__ xraw, const float* __restrict__ b3,
                                                 const float* __restrict__ wi, const float* __restrict__ bi,
                                                 const float* __restrict__ root_w, const float* __restrict__ root_b,
                                                 const float* __restrict__ bp2,
                                                 float* __restrict__ out_nce, float* __restrict__ U,
                                                 float* __restrict__ agg) {
  const int n = blockIdx.x, tid = threadIdx.x;
  float s[12] = {};
  for (int k = tid; k < 1024; k += 256) {
    float xv = xraw[n * 1024 + k] + b3[k];
#pragma unroll
    for (int c = 0; c < 4; ++c) {
      s[c] += xv * wi[k * 4 + c];
      s[4 + c] += xv * root_w[k * 4 + c];
      s[8 + c] += xv * bp2[k * 4 + c];
    }
  }
  __shared__ float part[4][12];
  const int lane = tid & 63, wv = tid >> 6;
#pragma unroll
  for (int r = 0; r < 12; ++r) {
    float v = s[r];
#pragma unroll
    for (int off = 32; off > 0; off >>= 1) v += __shfl_down(v, off, 64);
    if (lane == 0) part[wv][r] = v;
  }
  __syncthreads();
  if (tid < 12) {
    float v = part[0][tid] + part[1][tid] + part[2][tid] + part[3][tid];
    int kind = tid >> 2, c = tid & 3;
    if (kind == 0) out_nce[n * 4 + c] = sigf(v + bi[c]);
    else if (kind == 1) agg[n * 4 + c] = v + root_b[c];
    else U[n * 4 + c] = v;
  }
}

// ---------------- fused edge kernel: eh1 -> eh2 -> ea (out2) -> h -> msg -> agg ----------------
__global__ __launch_bounds__(256) void k_edge(const float* __restrict__ P, const float* __restrict__ Q,
                                              const float* __restrict__ we2, const float* __restrict__ be2,
                                              const float* __restrict__ we3, const float* __restrict__ be3,
                                              const float* __restrict__ wp1, const float* __restrict__ bp1,
                                              const float* __restrict__ pri,
                                              const float* __restrict__ T, const float* __restrict__ U,
                                              float* __restrict__ agg, float* __restrict__ out_ea) {
  __shared__ float As[64][68];   // eh1 chunk [edge][k]
  __shared__ float Bs[64][68];   // we2 chunk [k][col]
  __shared__ float Es[64][68];   // eh2 [edge][col]
  __shared__ int src_s[64], dst_s[64];
  __shared__ float ea_s[64][4];
  __shared__ float ps[256][4];

  const int tid = threadIdx.x;
  const int tx = tid & 15, ty = tid >> 4;
  const int e0 = blockIdx.x * 64;

  if (tid < 64) {
    int e = e0 + tid;
    int i = -1, j = 0;
    if (e < ETOT) {
      i = e / 199;
      int jj = e - i * 199;
      j = jj + (jj >= i ? 1 : 0);
    }
    src_s[tid] = i;
    dst_s[tid] = j;
  }
  __syncthreads();

  float acc[4][4] = {};
  const int cg = tid & 63;
  const int eg = (tid >> 6) * 16;

  for (int kcx = 0; kcx < 4; ++kcx) {
    const int kc0 = kcx * 64;
#pragma unroll
    for (int i2 = 0; i2 < 16; ++i2) {
      int e = tid + i2 * 256;
      int r = e >> 6, c = e & 63;
      Bs[r][c] = we2[(kc0 + r) * 64 + c];
    }
#pragma unroll
    for (int q = 0; q < 16; ++q) {
      int ee = eg + q;
      int i = src_s[ee], j = dst_s[ee];
      float v = 0.0f;
      if (i >= 0) v = fmaxf(P[i * 256 + kc0 + cg] + Q[j * 256 + kc0 + cg], 0.0f);
      As[ee][cg] = v;
    }
    __syncthreads();
#pragma unroll
    for (int k4 = 0; k4 < 16; ++k4) {
      float ar[4][4], br[4][4];
#pragma unroll
      for (int i = 0; i < 4; ++i) {
        float4 v = *(const float4*)&As[ty * 4 + i][k4 * 4];
        ar[i][0] = v.x; ar[i][1] = v.y; ar[i][2] = v.z; ar[i][3] = v.w;
      }
#pragma unroll
      for (int kq = 0; kq < 4; ++kq) {
        float4 v = *(const float4*)&Bs[k4 * 4 + kq][tx * 4];
        br[kq][0] = v.x; br[kq][1] = v.y; br[kq][2] = v.z; br[kq][3] = v.w;
      }
#pragma unroll
      for (int kq = 0; kq < 4; ++kq)
#pragma unroll
        for (int i = 0; i < 4; ++i)
#pragma unroll
          for (int j = 0; j < 4; ++j) acc[i][j] += ar[i][kq] * br[kq][j];
    }
    __syncthreads();
  }

  // eh2 = relu(acc + be2) -> Es
#pragma unroll
  for (int i = 0; i < 4; ++i) {
    float4 v;
    v.x = fmaxf(acc[i][0] + be2[tx * 4 + 0], 0.0f);
    v.y = fmaxf(acc[i][1] + be2[tx * 4 + 1], 0.0f);
    v.z = fmaxf(acc[i][2] + be2[tx * 4 + 2], 0.0f);
    v.w = fmaxf(acc[i][3] + be2[tx * 4 + 3], 0.0f);
    *(float4*)&Es[ty * 4 + i][tx * 4] = v;
  }
  __syncthreads();

  // per-edge tail: 4 threads per edge
  const int ee = tid >> 2, p = tid & 3;
  const int si = src_s[ee], dj = dst_s[ee];
  const int e = e0 + ee;
  float val;
  if (p < 3) {
    float sv = be3[p];
    for (int k = 0; k < 64; ++k) sv += Es[ee][k] * we3[k * 3 + p];
    val = sigf(sv);
  } else {
    val = 0.0f;
    if (si >= 0) val = (pri[si] > pri[dj]) ? 1.0f : 0.0f;
  }
  ea_s[ee][p] = val;
  if (si >= 0) out_ea[e * 4 + p] = val;
  __syncthreads();

  float pm0 = 0, pm1 = 0, pm2 = 0, pm3 = 0;
  if (si >= 0) {
    const float c0 = ea_s[ee][0], c1 = ea_s[ee][1], c2 = ea_s[ee][2], c3 = ea_s[ee][3];
    for (int t = p; t < 128; t += 4) {
      float hv = bp1[t] + c0 * wp1[t] + c1 * wp1[128 + t] +
                 c2 * wp1[256 + t] + c3 * wp1[384 + t];
      hv = fmaxf(hv, 0.0f);
      const float4 tv = *(const float4*)&T[si * 512 + t * 4];
      pm0 += hv * tv.x; pm1 += hv * tv.y; pm2 += hv * tv.z; pm3 += hv * tv.w;
    }
  }
  ps[tid][0] = pm0; ps[tid][1] = pm1; ps[tid][2] = pm2; ps[tid][3] = pm3;
  __syncthreads();
  if (si >= 0) {
    float m = U[si * 4 + p] + ps[ee * 4 + 0][p] + ps[ee * 4 + 1][p] + ps[ee * 4 + 2][p] + ps[ee * 4 + 3][p];
    atomicAdd(&agg[dj * 4 + p], m);
  }
}

// ---------------- finalize ----------------
__global__ void k_final(const float* __restrict__ agg, float* __restrict__ out0) {
  int t = blockIdx.x * 256 + threadIdx.x;
  if (t < 800) out0[t] = agg[t];
}

extern "C" void kernel_launch(void* const* d_in, const int* in_sizes, int n_in,
                              void* d_out, int out_size, void* d_ws, size_t ws_size,
                              hipStream_t stream) {
  (void)in_sizes; (void)n_in; (void)out_size; (void)ws_size;
  const float* roi   = (const float*)d_in[0];
  const float* bbox  = (const float*)d_in[1];
  const float* dir   = (const float*)d_in[2];
  const float* pri   = (const float*)d_in[3];
  const float* w1    = (const float*)d_in[4];
  const float* b1    = (const float*)d_in[5];
  const float* w2    = (const float*)d_in[6];
  const float* b2    = (const float*)d_in[7];
  const float* w3    = (const float*)d_in[8];
  const float* b3    = (const float*)d_in[9];
  const float* wi    = (const float*)d_in[10];
  const float* bi    = (const float*)d_in[11];
  const float* we1   = (const float*)d_in[12];
  const float* be1   = (const float*)d_in[13];
  const float* we2   = (const float*)d_in[14];
  const float* be2   = (const float*)d_in[15];
  const float* we3   = (const float*)d_in[16];
  const float* be3   = (const float*)d_in[17];
  const float* wp1   = (const float*)d_in[18];
  const float* bp1   = (const float*)d_in[19];
  const float* wp2   = (const float*)d_in[20];
  const float* bp2   = (const float*)d_in[21];
  const float* rootw = (const float*)d_in[22];
  const float* rootb = (const float*)d_in[23];

  float* out0 = (float*)d_out;        // next_actions [200,4]
  float* out1 = out0 + 800;           // node_concepts_explicit[0] [200,4]
  float* out2 = out0 + 1600;          // edge_attributes[0] [39800,4]

  float* ws = (float*)d_ws;
  float* C1 = ws;                 // [200,512]   raw (no bias/relu)
  float* C2 = ws + 102400;        // [200,256]   raw
  float* XR = ws + 153600;        // [200,1024]  raw (x = XR + b3)
  float* Tm = ws + 358400;        // [200,512]   T
  float* Wr = ws + 460800;        // [1024,512]
  float* Pm = ws + 985088;        // [200,256]
  float* Qm = ws + 1036288;       // [200,256]
  float* Um = ws + 1087488;       // [200,4]
  float* Ag = ws + 1088288;       // [200,4]

  // zero the atomic-accumulated buffers (C1,C2,XR,Tm contiguous: 460800 floats)
  k_zero<<<1800, 256, 0, stream>>>(ws, 460800);
  k_shuffle<<<2048, 256, 0, stream>>>(wp2, Wr);
  k_PQ<<<200, 256, 0, stream>>>(bbox, dir, we1, be1, Pm, Qm);

  // node MLP chain (bias/relu folded into next consumer's A-loader)
  gemm_ks<0><<<dim3(4, 8, 8), 256, 0, stream>>>(roi, nullptr, w1, C1, 200, 512, 2048, 256);
  gemm_ks<1><<<dim3(4, 4, 8), 256, 0, stream>>>(C1, b1, w2, C2, 200, 256, 512, 64);
  gemm_ks<1><<<dim3(4, 16, 4), 256, 0, stream>>>(C2, b2, w3, XR, 200, 1024, 256, 64);

  // per-node vectors: nce output, U, agg init
  k_nodevec<<<200, 256, 0, stream>>>(XR, b3, wi, bi, rootw, rootb, bp2, out1, Um, Ag);

  // T = (XR + b3) @ Wr
  gemm_ks<2><<<dim3(4, 8, 8), 256, 0, stream>>>(XR, b3, Wr, Tm, 200, 512, 1024, 128);

  // fused edge pipeline
  k_edge<<<622, 256, 0, stream>>>(Pm, Qm, we2, be2, we3, be3, wp1, bp1, pri, Tm, Um, Ag, out2);

  k_final<<<4, 256, 0, stream>>>(Ag, out0);
}

// Round 3
// 275.218 us; speedup vs baseline: 1.0803x; 1.0803x over previous
//
#include <hip/hip_runtime.h>
#include <math.h>

#define NN 200
#define ETOT 39800

typedef float float4v __attribute__((ext_vector_type(4)));
typedef short short8 __attribute__((ext_vector_type(8)));

__device__ __forceinline__ float sigf(float x) { return 1.0f / (1.0f + expf(-x)); }

__device__ __forceinline__ unsigned short f2b(float f) {
  unsigned u = __float_as_uint(f);
  u += 0x7fffu + ((u >> 16) & 1u);
  return (unsigned short)(u >> 16);
}

// ---------------- merged prep: zero | Wr shuffle | we2T bf16 | P/Q ----------------
// blocks [0,450): zero ws[0,460800) as float4
// blocks [450,962): Wr[i][k*4+o] = wp2[k][i*4+o], float4 over o (coalesced reads)
// blocks [962,978): we2T[c][k] = bf16(we2[k][c]), [64][256]
// blocks [978,1178): P/Q per node
__global__ __launch_bounds__(256) void k_prep(
    const float* __restrict__ wp2, float* __restrict__ Wr,
    const float* __restrict__ we2, unsigned short* __restrict__ we2T,
    const float* __restrict__ bbox, const float* __restrict__ dir,
    const float* __restrict__ we1, const float* __restrict__ be1,
    float* __restrict__ P, float* __restrict__ Q, float* __restrict__ zb) {
  const int b = blockIdx.x, tid = threadIdx.x;
  if (b < 450) {
    int i = b * 256 + tid;                       // 115200 float4 = 460800 floats
    float4v z = {0.f, 0.f, 0.f, 0.f};
    ((float4v*)zb)[i] = z;
  } else if (b < 962) {
    int f = (b - 450) * 256 + tid;               // 131072 float4
    int i = f >> 7;                              // 0..1023
    int k = f & 127;                             // 0..127
    float4v v = ((const float4v*)wp2)[k * 1024 + i];   // wp2[k*4096 + i*4 .. +3]
    ((float4v*)Wr)[i * 128 + k] = v;                   // Wr[i*512 + k*4 .. +3]
  } else if (b < 978) {
    int f = (b - 962) * 256 + tid;               // 0..4095
    int c = f >> 6;                              // 0..63
    int k0 = (f & 63) * 4;
#pragma unroll
    for (int q = 0; q < 4; ++q)
      we2T[c * 256 + k0 + q] = f2b(we2[(k0 + q) * 64 + c]);
  } else {
    int n = b - 978, c = tid;
    float a[8];
#pragma unroll
    for (int r = 0; r < 4; ++r) a[r] = bbox[n * 4 + r] * (1.0f / 1024.0f);
#pragma unroll
    for (int r = 0; r < 4; ++r) a[4 + r] = dir[n * 4 + r];
    float p = be1[c], q = 0.0f;
#pragma unroll
    for (int r = 0; r < 8; ++r) {
      p += a[r] * we1[r * 256 + c];
      q += a[r] * we1[(8 + r) * 256 + c];
    }
    P[n * 256 + c] = p;
    Q[n * 256 + c] = q;
  }
}

// ---------------- K-split tiled GEMM, atomicAdd partials into pre-zeroed C ----------------
// AMODE: 0 = A plain; 1 = A + bias + relu; 2 = A + bias
template <int AMODE>
__global__ __launch_bounds__(256) void gemm_ks(const float* __restrict__ A, const float* __restrict__ Abias,
                                               const float* __restrict__ Bp, float* __restrict__ C,
                                               int M, int N, int K, int KC) {
  __shared__ float As[64][33];
  __shared__ float Bs[32][64];
  const int m0 = blockIdx.x * 64, n0 = blockIdx.y * 64, k0 = blockIdx.z * KC;
  const int tid = threadIdx.x, tx = tid & 15, ty = tid >> 4;
  float acc[4][4] = {};

  for (int kk = k0; kk < k0 + KC; kk += 32) {
#pragma unroll
    for (int i = 0; i < 8; ++i) {
      int e = tid + i * 256;
      int r = e >> 5, c = e & 31;
      int m = m0 + r, k = kk + c;
      float v = 0.0f;
      if (m < M) {
        v = A[(size_t)m * K + k];
        if (AMODE != 0) {
          v += Abias[k];
          if (AMODE == 1) v = fmaxf(v, 0.0f);
        }
      }
      As[r][c] = v;
    }
#pragma unroll
    for (int i = 0; i < 8; ++i) {
      int e = tid + i * 256;
      int r = e >> 6, c = e & 63;
      Bs[r][c] = Bp[(size_t)(kk + r) * N + n0 + c];
    }
    __syncthreads();
#pragma unroll
    for (int k = 0; k < 32; ++k) {
      float a[4];
#pragma unroll
      for (int i = 0; i < 4; ++i) a[i] = As[ty * 4 + i][k];
      const float4 b4 = *(const float4*)&Bs[k][tx * 4];
      const float b[4] = {b4.x, b4.y, b4.z, b4.w};
#pragma unroll
      for (int i = 0; i < 4; ++i)
#pragma unroll
        for (int j = 0; j < 4; ++j) acc[i][j] += a[i] * b[j];
    }
    __syncthreads();
  }
#pragma unroll
  for (int i = 0; i < 4; ++i) {
    int m = m0 + ty * 4 + i;
    if (m < M) {
#pragma unroll
      for (int j = 0; j < 4; ++j) atomicAdd(&C[(size_t)m * N + n0 + tx * 4 + j], acc[i][j]);
    }
  }
}

// ---------------- per-node vectors: nce (output 1), U, agg init ----------------
__global__ __launch_bounds__(256) void k_nodevec(const float* __restrict__ xraw, const float* __restrict__ b3,
                                                 const float* __restrict__ wi, const float* __restrict__ bi,
                                                 const float* __restrict__ root_w, const float* __restrict__ root_b,
                                                 const float* __restrict__ bp2,
                                                 float* __restrict__ out_nce, float* __restrict__ U,
                                                 float* __restrict__ agg) {
  const int n = blockIdx.x, tid = threadIdx.x;
  float s[12] = {};
  for (int k = tid; k < 1024; k += 256) {
    float xv = xraw[n * 1024 + k] + b3[k];
#pragma unroll
    for (int c = 0; c < 4; ++c) {
      s[c] += xv * wi[k * 4 + c];
      s[4 + c] += xv * root_w[k * 4 + c];
      s[8 + c] += xv * bp2[k * 4 + c];
    }
  }
  __shared__ float part[4][12];
  const int lane = tid & 63, wv = tid >> 6;
#pragma unroll
  for (int r = 0; r < 12; ++r) {
    float v = s[r];
#pragma unroll
    for (int off = 32; off > 0; off >>= 1) v += __shfl_down(v, off, 64);
    if (lane == 0) part[wv][r] = v;
  }
  __syncthreads();
  if (tid < 12) {
    float v = part[0][tid] + part[1][tid] + part[2][tid] + part[3][tid];
    int kind = tid >> 2, c = tid & 3;
    if (kind == 0) out_nce[n * 4 + c] = sigf(v + bi[c]);
    else if (kind == 1) agg[n * 4 + c] = v + root_b[c];
    else U[n * 4 + c] = v;
  }
}

// ---------------- fused edge kernel (MFMA): eh1 -> eh2 -> ea (out2) -> h -> msg -> agg ----------------
__global__ __launch_bounds__(256) void k_edge(
    const float* __restrict__ P, const float* __restrict__ Q,
    const unsigned short* __restrict__ we2T,
    const float* __restrict__ be2, const float* __restrict__ we3, const float* __restrict__ be3,
    const float* __restrict__ wp1, const float* __restrict__ bp1,
    const float* __restrict__ pri,
    const float* __restrict__ T, const float* __restrict__ U,
    float* __restrict__ agg, float* __restrict__ out_ea) {
  __shared__ int src_s[64], dst_s[64];
  __shared__ float ea_s[64][4];

  const int tid = threadIdx.x;
  const int e0 = blockIdx.x * 64;
  if (tid < 64) {
    int e = e0 + tid;
    int i = -1, j = 0;
    if (e < ETOT) {
      i = e / 199;
      int jj = e - i * 199;
      j = jj + (jj >= i ? 1 : 0);
    }
    src_s[tid] = i;
    dst_s[tid] = j;
  }
  __syncthreads();

  const int lane = tid & 63;
  const int wv = tid >> 6;          // wave id, owns edges wv*16..wv*16+15
  const int m = lane & 15;          // A row / B col / C col index
  const int quad = lane >> 4;
  const int eloc = wv * 16 + m;
  const int si = src_s[eloc];
  const int dj = dst_s[eloc];

  float4v acc[4];
#pragma unroll
  for (int ct = 0; ct < 4; ++ct) { acc[ct][0] = 0.f; acc[ct][1] = 0.f; acc[ct][2] = 0.f; acc[ct][3] = 0.f; }

  const short8* W8 = (const short8*)we2T;

  // GEMM: eh2_raw[64 edges][64 cols] = eh1 @ we2, K=256, 8 k-steps of 32
  for (int ks = 0; ks < 8; ++ks) {
    short8 af = (short8)0;
    if (si >= 0) {
      const float4v* p4 = (const float4v*)(P + si * 256 + ks * 32 + quad * 8);
      const float4v* q4 = (const float4v*)(Q + dj * 256 + ks * 32 + quad * 8);
      float4v v0 = p4[0] + q4[0];
      float4v v1 = p4[1] + q4[1];
#pragma unroll
      for (int j = 0; j < 4; ++j) {
        af[j] = (short)f2b(fmaxf(v0[j], 0.f));
        af[4 + j] = (short)f2b(fmaxf(v1[j], 0.f));
      }
    }
#pragma unroll
    for (int ct = 0; ct < 4; ++ct) {
      short8 bf = W8[(ct * 16 + m) * 32 + ks * 4 + quad];
      acc[ct] = __builtin_amdgcn_mfma_f32_16x16x32_bf16(af, bf, acc[ct], 0, 0, 0);
    }
  }

  // epilogue: eh2 = relu(acc + be2); ev = eh2 @ we3 (reduce over 64 cols via shfl)
  float ev[4][3];
#pragma unroll
  for (int r = 0; r < 4; ++r) { ev[r][0] = 0.f; ev[r][1] = 0.f; ev[r][2] = 0.f; }
#pragma unroll
  for (int ct = 0; ct < 4; ++ct) {
    const int col = ct * 16 + m;
    const float b2v = be2[col];
    const float w0 = we3[col * 3 + 0], w1v = we3[col * 3 + 1], w2v = we3[col * 3 + 2];
#pragma unroll
    for (int r = 0; r < 4; ++r) {
      float e2 = fmaxf(acc[ct][r] + b2v, 0.f);
      ev[r][0] += e2 * w0;
      ev[r][1] += e2 * w1v;
      ev[r][2] += e2 * w2v;
    }
  }
#pragma unroll
  for (int r = 0; r < 4; ++r)
#pragma unroll
    for (int p = 0; p < 3; ++p) {
      float v = ev[r][p];
      v += __shfl_xor(v, 1, 64);
      v += __shfl_xor(v, 2, 64);
      v += __shfl_xor(v, 4, 64);
      v += __shfl_xor(v, 8, 64);
      ev[r][p] = v;
    }
  // lane m==0 of each quad writes 4 edges (rows quad*4+r) of out2 + ea_s
  if (m == 0) {
#pragma unroll
    for (int r = 0; r < 4; ++r) {
      int el = wv * 16 + quad * 4 + r;
      int ss = src_s[el], dd = dst_s[el];
      if (ss >= 0) {
        float4v o;
        o[0] = sigf(ev[r][0] + be3[0]);
        o[1] = sigf(ev[r][1] + be3[1]);
        o[2] = sigf(ev[r][2] + be3[2]);
        o[3] = (pri[ss] > pri[dd]) ? 1.0f : 0.0f;
        *(float4v*)&ea_s[el][0] = o;
        *(float4v*)(out_ea + (size_t)(e0 + el) * 4) = o;
      }
    }
  }
  __syncthreads();

  // tail: h = relu(bp1 + ea@wp1) [128], msg = h @ T[src] [4]; 4 threads per edge
  const int ee = tid >> 2, pp = tid & 3;
  const int s2 = src_s[ee], d2 = dst_s[ee];
  float4v pm = {0.f, 0.f, 0.f, 0.f};
  if (s2 >= 0) {
    const float c0 = ea_s[ee][0], c1 = ea_s[ee][1], c2 = ea_s[ee][2], c3 = ea_s[ee][3];
    const float4v* T4 = (const float4v*)(T + s2 * 512);
    for (int t = pp; t < 128; t += 4) {
      float hv = bp1[t] + c0 * wp1[t] + c1 * wp1[128 + t] + c2 * wp1[256 + t] + c3 * wp1[384 + t];
      hv = fmaxf(hv, 0.f);
      pm += hv * T4[t];
    }
  }
#pragma unroll
  for (int o = 0; o < 4; ++o) {
    float v = pm[o];
    v += __shfl_xor(v, 1, 64);
    v += __shfl_xor(v, 2, 64);
    pm[o] = v;
  }
  if (s2 >= 0) atomicAdd(&agg[d2 * 4 + pp], U[s2 * 4 + pp] + pm[pp]);
}

// ---------------- finalize ----------------
__global__ void k_final(const float* __restrict__ agg, float* __restrict__ out0) {
  int t = blockIdx.x * 256 + threadIdx.x;
  if (t < 800) out0[t] = agg[t];
}

extern "C" void kernel_launch(void* const* d_in, const int* in_sizes, int n_in,
                              void* d_out, int out_size, void* d_ws, size_t ws_size,
                              hipStream_t stream) {
  (void)in_sizes; (void)n_in; (void)out_size; (void)ws_size;
  const float* roi   = (const float*)d_in[0];
  const float* bbox  = (const float*)d_in[1];
  const float* dir   = (const float*)d_in[2];
  const float* pri   = (const float*)d_in[3];
  const float* w1    = (const float*)d_in[4];
  const float* b1    = (const float*)d_in[5];
  const float* w2    = (const float*)d_in[6];
  const float* b2    = (const float*)d_in[7];
  const float* w3    = (const float*)d_in[8];
  const float* b3    = (const float*)d_in[9];
  const float* wi    = (const float*)d_in[10];
  const float* bi    = (const float*)d_in[11];
  const float* we1   = (const float*)d_in[12];
  const float* be1   = (const float*)d_in[13];
  const float* we2   = (const float*)d_in[14];
  const float* be2   = (const float*)d_in[15];
  const float* we3   = (const float*)d_in[16];
  const float* be3   = (const float*)d_in[17];
  const float* wp1   = (const float*)d_in[18];
  const float* bp1   = (const float*)d_in[19];
  const float* wp2   = (const float*)d_in[20];
  const float* bp2   = (const float*)d_in[21];
  const float* rootw = (const float*)d_in[22];
  const float* rootb = (const float*)d_in[23];

  float* out0 = (float*)d_out;        // next_actions [200,4]
  float* out1 = out0 + 800;           // node_concepts_explicit[0] [200,4]
  float* out2 = out0 + 1600;          // edge_attributes[0] [39800,4]

  float* ws = (float*)d_ws;
  float* C1 = ws;                       // [200,512]   raw
  float* C2 = ws + 102400;              // [200,256]   raw
  float* XR = ws + 153600;              // [200,1024]  raw (x = XR + b3)
  float* Tm = ws + 358400;              // [200,512]
  float* Wr = ws + 460800;              // [1024,512]
  float* Pm = ws + 985088;              // [200,256]
  float* Qm = ws + 1036288;             // [200,256]
  float* Um = ws + 1087488;             // [200,4]
  float* Ag = ws + 1088288;             // [200,4]
  unsigned short* We2T = (unsigned short*)(ws + 1089088);  // [64,256] bf16, 16B-aligned

  // prep: zero C1..Tm | Wr shuffle | we2T | P/Q   (450+512+16+200 blocks)
  k_prep<<<1178, 256, 0, stream>>>(wp2, Wr, we2, We2T, bbox, dir, we1, be1, Pm, Qm, ws);

  // node MLP chain (bias/relu folded into next consumer's A-loader)
  gemm_ks<0><<<dim3(4, 8, 16), 256, 0, stream>>>(roi, nullptr, w1, C1, 200, 512, 2048, 128);
  gemm_ks<1><<<dim3(4, 4, 16), 256, 0, stream>>>(C1, b1, w2, C2, 200, 256, 512, 32);
  gemm_ks<1><<<dim3(4, 16, 8), 256, 0, stream>>>(C2, b2, w3, XR, 200, 1024, 256, 32);

  // per-node vectors: nce output, U, agg init
  k_nodevec<<<200, 256, 0, stream>>>(XR, b3, wi, bi, rootw, rootb, bp2, out1, Um, Ag);

  // T = (XR + b3) @ Wr
  gemm_ks<2><<<dim3(4, 8, 16), 256, 0, stream>>>(XR, b3, Wr, Tm, 200, 512, 1024, 64);

  // fused edge pipeline (MFMA)
  k_edge<<<622, 256, 0, stream>>>(Pm, Qm, We2T, be2, we3, be3, wp1, bp1, pri, Tm, Um, Ag, out2);

  k_final<<<4, 256, 0, stream>>>(Ag, out0);
}

// Round 5
// 157.171 us; speedup vs baseline: 1.8917x; 1.7511x over previous
//
#include <hip/hip_runtime.h>
#include <math.h>

#define NN 200
#define ETOT 39800

typedef float float4v __attribute__((ext_vector_type(4)));
typedef short short8 __attribute__((ext_vector_type(8)));
typedef unsigned int uint4v __attribute__((ext_vector_type(4)));

__device__ __forceinline__ float sigf(float x) { return 1.0f / (1.0f + expf(-x)); }

__device__ __forceinline__ unsigned short f2b(float f) {
  unsigned u = __float_as_uint(f);
  u += 0x7fffu + ((u >> 16) & 1u);
  return (unsigned short)(u >> 16);
}
__device__ __forceinline__ float b2f16(unsigned short u) {
  return __uint_as_float(((unsigned)u) << 16);
}
__device__ __forceinline__ unsigned pkbf(float a, float b) {
  return (unsigned)f2b(a) | ((unsigned)f2b(b) << 16);
}

// ======================= prep: transposes + conversions + P/Q =======================
// blocks [0,256): w1 [2048][512] -> w1T bf16 [512][2048]
// blocks [256,288): w2 [512][256] -> w2T bf16 [256][512]
// blocks [288,352): w3 [256][1024] -> w3T bf16 [1024][256]
// blocks [352,480): wp2 [128][4096] -> WrT bf16 [512][1024], WrT[k*4+o][i]=wp2[k][i*4+o]
// blocks [480,496): we2 [256][64] -> we2T bf16 [64][256]
// blocks [496,696): P/Q per node
// blocks [696,896): roi row -> bf16
// block  896: wp1T float4[128]
__global__ __launch_bounds__(256) void k_prep(
    const float* __restrict__ w1, const float* __restrict__ w2, const float* __restrict__ w3,
    const float* __restrict__ wp2, const float* __restrict__ we2,
    const float* __restrict__ bbox, const float* __restrict__ dir,
    const float* __restrict__ we1, const float* __restrict__ be1,
    const float* __restrict__ roi, const float* __restrict__ wp1,
    unsigned short* __restrict__ w1T, unsigned short* __restrict__ w2T,
    unsigned short* __restrict__ w3T, unsigned short* __restrict__ WrT,
    unsigned short* __restrict__ we2T, unsigned short* __restrict__ roiB,
    float* __restrict__ P, float* __restrict__ Q, float* __restrict__ wp1T) {
  __shared__ float lds[64][65];
  const int b = blockIdx.x, tid = threadIdx.x;

  if (b < 352) {
    // LDS-tiled transpose f32[K][N] -> bf16[N][K]
    const float* Wf;
    unsigned short* Wt;
    int K, N, t;
    if (b < 256) { Wf = w1; Wt = w1T; K = 2048; N = 512; t = b; }
    else if (b < 288) { Wf = w2; Wt = w2T; K = 512; N = 256; t = b - 256; }
    else { Wf = w3; Wt = w3T; K = 256; N = 1024; t = b - 288; }
    const int K64 = K >> 6;
    const int kt = t % K64, nt = t / K64;
#pragma unroll 4
    for (int i = 0; i < 16; ++i) {
      int idx = tid + i * 256;
      int r = idx >> 6, c = idx & 63;
      lds[r][c] = Wf[(size_t)(kt * 64 + r) * N + nt * 64 + c];
    }
    __syncthreads();
#pragma unroll 4
    for (int i = 0; i < 16; ++i) {
      int idx = tid + i * 256;
      int r = idx >> 6, c = idx & 63;
      Wt[(size_t)(nt * 64 + r) * K + kt * 64 + c] = f2b(lds[c][r]);
    }
  } else if (b < 480) {
    int k = b - 352;                         // 0..127
    int o = tid >> 6, l = tid & 63;
    const float* src = wp2 + (size_t)k * 4096;
    unsigned short* dst = WrT + (size_t)(k * 4 + o) * 1024;
    for (int i = l; i < 1024; i += 64) dst[i] = f2b(src[i * 4 + o]);
  } else if (b < 496) {
    int f = (b - 480) * 256 + tid;           // 0..4095
    int c = f >> 6, k0 = (f & 63) * 4;
#pragma unroll
    for (int q = 0; q < 4; ++q)
      we2T[c * 256 + k0 + q] = f2b(we2[(k0 + q) * 64 + c]);
  } else if (b < 696) {
    int n = b - 496, c = tid;
    float a[8];
#pragma unroll
    for (int r = 0; r < 4; ++r) a[r] = bbox[n * 4 + r] * (1.0f / 1024.0f);
#pragma unroll
    for (int r = 0; r < 4; ++r) a[4 + r] = dir[n * 4 + r];
    float p = be1[c], q = 0.0f;
#pragma unroll
    for (int r = 0; r < 8; ++r) {
      p += a[r] * we1[r * 256 + c];
      q += a[r] * we1[(8 + r) * 256 + c];
    }
    P[n * 256 + c] = p;
    Q[n * 256 + c] = q;
  } else if (b < 896) {
    int n = b - 696;
    const float4v* R4 = (const float4v*)(roi + (size_t)n * 2048);
    unsigned long long* O = (unsigned long long*)(roiB + (size_t)n * 2048);
#pragma unroll
    for (int j = 0; j < 2; ++j) {
      int idx = tid + j * 256;
      float4v v = R4[idx];
      union { unsigned short us[4]; unsigned long long ll; } pk;
#pragma unroll
      for (int q = 0; q < 4; ++q) pk.us[q] = f2b(v[q]);
      O[idx] = pk.ll;
    }
  } else {
    if (tid < 128) {
      float4v v = {wp1[tid], wp1[128 + tid], wp1[256 + tid], wp1[384 + tid]};
      ((float4v*)wp1T)[tid] = v;
    }
  }
}

// ======================= MFMA GEMM, 16x16 out tile, waves split K 4-way =======================
// A bf16 [208][K] row-major, B bf16 [N][K] (i.e. W^T), out bf16 [208][N] or f32 [208][N]
template <int KSTEPS, int RELU, int OUTF32, int HASBIAS>
__global__ __launch_bounds__(256) void gemm_mf(const unsigned short* __restrict__ A,
                                               const unsigned short* __restrict__ B,
                                               const float* __restrict__ bias,
                                               void* __restrict__ Cout, int N) {
  constexpr int K = KSTEPS * 128;
  const int tid = threadIdx.x, lane = tid & 63, wv = tid >> 6;
  const int m0 = blockIdx.x * 16, n0 = blockIdx.y * 16;
  const int mr = lane & 15, quad = lane >> 4;
  const unsigned short* Ap = A + (size_t)(m0 + mr) * K + wv * (KSTEPS * 32) + quad * 8;
  const unsigned short* Bp = B + (size_t)(n0 + mr) * K + wv * (KSTEPS * 32) + quad * 8;
  float4v acc = {0.f, 0.f, 0.f, 0.f};
#pragma unroll
  for (int s = 0; s < KSTEPS; ++s) {
    short8 af = *(const short8*)(Ap + s * 32);
    short8 bf = *(const short8*)(Bp + s * 32);
    acc = __builtin_amdgcn_mfma_f32_16x16x32_bf16(af, bf, acc, 0, 0, 0);
  }
  __shared__ float red[4][16][17];
#pragma unroll
  for (int r = 0; r < 4; ++r) red[wv][quad * 4 + r][mr] = acc[r];
  __syncthreads();
  const int row = tid >> 4, col = tid & 15;
  float v = red[0][row][col] + red[1][row][col] + red[2][row][col] + red[3][row][col];
  if (HASBIAS) v += bias[n0 + col];
  if (RELU) v = fmaxf(v, 0.f);
  if (OUTF32)
    ((float*)Cout)[(size_t)(m0 + row) * N + n0 + col] = v;
  else
    ((unsigned short*)Cout)[(size_t)(m0 + row) * N + n0 + col] = f2b(v);
}

// ======================= per-node: nce (out1), U, agg-init -> out0 =======================
__global__ __launch_bounds__(256) void k_nodevec(const unsigned short* __restrict__ xB,
                                                 const float* __restrict__ wi, const float* __restrict__ bi,
                                                 const float* __restrict__ root_w, const float* __restrict__ root_b,
                                                 const float* __restrict__ bp2,
                                                 float* __restrict__ out_nce, float* __restrict__ U,
                                                 float* __restrict__ out0) {
  const int n = blockIdx.x, tid = threadIdx.x;
  float s[12] = {};
#pragma unroll
  for (int i = 0; i < 4; ++i) {
    int k = tid + i * 256;
    float xv = b2f16(xB[n * 1024 + k]);
    float4v wi4 = ((const float4v*)wi)[k];
    float4v rw4 = ((const float4v*)root_w)[k];
    float4v bp4 = ((const float4v*)bp2)[k];
#pragma unroll
    for (int c = 0; c < 4; ++c) {
      s[c] += xv * wi4[c];
      s[4 + c] += xv * rw4[c];
      s[8 + c] += xv * bp4[c];
    }
  }
  __shared__ float part[4][12];
  const int lane = tid & 63, wv = tid >> 6;
#pragma unroll
  for (int r = 0; r < 12; ++r) {
    float v = s[r];
#pragma unroll
    for (int off = 32; off > 0; off >>= 1) v += __shfl_down(v, off, 64);
    if (lane == 0) part[wv][r] = v;
  }
  __syncthreads();
  if (tid < 12) {
    float v = part[0][tid] + part[1][tid] + part[2][tid] + part[3][tid];
    int kind = tid >> 2, c = tid & 3;
    if (kind == 0) out_nce[n * 4 + c] = sigf(v + bi[c]);
    else if (kind == 1) out0[n * 4 + c] = v + root_b[c];
    else U[n * 4 + c] = v;
  }
}

// ======================= fused edge kernel (MFMA + LDS-staged tail) =======================
__global__ __launch_bounds__(256) void k_edge(
    const float* __restrict__ P, const float* __restrict__ Q,
    const unsigned short* __restrict__ we2T,
    const float* __restrict__ be2, const float* __restrict__ we3, const float* __restrict__ be3,
    const float* __restrict__ wp1T, const float* __restrict__ bp1,
    const float* __restrict__ pri,
    const float* __restrict__ T, const float* __restrict__ U,
    float* __restrict__ out0, float* __restrict__ out_ea) {
  __shared__ int src_s[64], dst_s[64];
  __shared__ float ea_s[64][4];
  __shared__ float4v wp1s[128];
  __shared__ float bp1s[128];
  __shared__ float4v Ts[2][128];
  __shared__ float Us[2][4];

  const int tid = threadIdx.x;
  const int e0 = blockIdx.x * 64;
  const int s_lo = e0 / 199;

  if (tid < 64) {
    int e = e0 + tid;
    int i = -1, j = 0;
    if (e < ETOT) {
      i = e / 199;
      int jj = e - i * 199;
      j = jj + (jj >= i ? 1 : 0);
    }
    src_s[tid] = i;
    dst_s[tid] = j;
  }
  if (tid < 128) {
    wp1s[tid] = ((const float4v*)wp1T)[tid];
    bp1s[tid] = bp1[tid];
  }
  {
    int row = tid >> 7, c = tid & 127;
    Ts[row][c] = ((const float4v*)T)[(s_lo + row) * 128 + c];  // row s_lo+1 may read pad (T has 208 rows)
  }
  if (tid < 8) {
    int s = min(s_lo + (tid >> 2), 199);
    Us[tid >> 2][tid & 3] = U[s * 4 + (tid & 3)];
  }
  __syncthreads();

  const int lane = tid & 63;
  const int wv = tid >> 6;
  const int m = lane & 15;
  const int quad = lane >> 4;
  const int eloc = wv * 16 + m;
  const int si = src_s[eloc];
  const int dj = dst_s[eloc];

  float4v acc[4];
#pragma unroll
  for (int ct = 0; ct < 4; ++ct) { acc[ct][0] = 0.f; acc[ct][1] = 0.f; acc[ct][2] = 0.f; acc[ct][3] = 0.f; }

  const short8* W8 = (const short8*)we2T;

  for (int ks = 0; ks < 8; ++ks) {
    union { short8 s; uint4v u; } af;
    af.s = (short8)0;
    if (si >= 0) {
      const float4v* p4 = (const float4v*)(P + si * 256 + ks * 32 + quad * 8);
      const float4v* q4 = (const float4v*)(Q + dj * 256 + ks * 32 + quad * 8);
      float4v v0 = p4[0] + q4[0];
      float4v v1 = p4[1] + q4[1];
      af.u[0] = pkbf(fmaxf(v0[0], 0.f), fmaxf(v0[1], 0.f));
      af.u[1] = pkbf(fmaxf(v0[2], 0.f), fmaxf(v0[3], 0.f));
      af.u[2] = pkbf(fmaxf(v1[0], 0.f), fmaxf(v1[1], 0.f));
      af.u[3] = pkbf(fmaxf(v1[2], 0.f), fmaxf(v1[3], 0.f));
    }
#pragma unroll
    for (int ct = 0; ct < 4; ++ct) {
      short8 bf = W8[(ct * 16 + m) * 32 + ks * 4 + quad];
      acc[ct] = __builtin_amdgcn_mfma_f32_16x16x32_bf16(af.s, bf, acc[ct], 0, 0, 0);
    }
  }

  // eh2 = relu(acc + be2); ev = eh2 @ we3 (shfl-reduce over 64 cols)
  float ev[4][3];
#pragma unroll
  for (int r = 0; r < 4; ++r) { ev[r][0] = 0.f; ev[r][1] = 0.f; ev[r][2] = 0.f; }
#pragma unroll
  for (int ct = 0; ct < 4; ++ct) {
    const int col = ct * 16 + m;
    const float b2v = be2[col];
    const float w0 = we3[col * 3 + 0], w1v = we3[col * 3 + 1], w2v = we3[col * 3 + 2];
#pragma unroll
    for (int r = 0; r < 4; ++r) {
      float e2 = fmaxf(acc[ct][r] + b2v, 0.f);
      ev[r][0] += e2 * w0;
      ev[r][1] += e2 * w1v;
      ev[r][2] += e2 * w2v;
    }
  }
#pragma unroll
  for (int r = 0; r < 4; ++r)
#pragma unroll
    for (int p = 0; p < 3; ++p) {
      float v = ev[r][p];
      v += __shfl_xor(v, 1, 64);
      v += __shfl_xor(v, 2, 64);
      v += __shfl_xor(v, 4, 64);
      v += __shfl_xor(v, 8, 64);
      ev[r][p] = v;
    }
  if (m == 0) {
#pragma unroll
    for (int r = 0; r < 4; ++r) {
      int el = wv * 16 + quad * 4 + r;
      int ss = src_s[el], dd = dst_s[el];
      if (ss >= 0) {
        float4v o;
        o[0] = sigf(ev[r][0] + be3[0]);
        o[1] = sigf(ev[r][1] + be3[1]);
        o[2] = sigf(ev[r][2] + be3[2]);
        o[3] = (pri[ss] > pri[dd]) ? 1.0f : 0.0f;
        *(float4v*)&ea_s[el][0] = o;
        *(float4v*)(out_ea + (size_t)(e0 + el) * 4) = o;
      }
    }
  }
  __syncthreads();

  // tail: h = relu(bp1 + ea@wp1) [128]; msg = h @ T[src]; 4 threads/edge, all LDS
  const int ee = tid >> 2, pp = tid & 3;
  const int s2 = src_s[ee], d2 = dst_s[ee];
  float4v pm = {0.f, 0.f, 0.f, 0.f};
  if (s2 >= 0) {
    const int srow = s2 - s_lo;
    const float c0 = ea_s[ee][0], c1 = ea_s[ee][1], c2 = ea_s[ee][2], c3 = ea_s[ee][3];
#pragma unroll 8
    for (int t = pp; t < 128; t += 4) {
      float4v w4 = wp1s[t];
      float hv = bp1s[t] + c0 * w4[0] + c1 * w4[1] + c2 * w4[2] + c3 * w4[3];
      hv = fmaxf(hv, 0.f);
      pm += hv * Ts[srow][t];
    }
  }
#pragma unroll
  for (int o = 0; o < 4; ++o) {
    float v = pm[o];
    v += __shfl_xor(v, 1, 64);
    v += __shfl_xor(v, 2, 64);
    pm[o] = v;
  }
  if (s2 >= 0) atomicAdd(&out0[d2 * 4 + pp], Us[s2 - s_lo][pp] + pm[pp]);
}

extern "C" void kernel_launch(void* const* d_in, const int* in_sizes, int n_in,
                              void* d_out, int out_size, void* d_ws, size_t ws_size,
                              hipStream_t stream) {
  (void)in_sizes; (void)n_in; (void)out_size; (void)ws_size;
  const float* roi   = (const float*)d_in[0];
  const float* bbox  = (const float*)d_in[1];
  const float* dir   = (const float*)d_in[2];
  const float* pri   = (const float*)d_in[3];
  const float* w1    = (const float*)d_in[4];
  const float* b1    = (const float*)d_in[5];
  const float* w2    = (const float*)d_in[6];
  const float* b2    = (const float*)d_in[7];
  const float* w3    = (const float*)d_in[8];
  const float* b3    = (const float*)d_in[9];
  const float* wi    = (const float*)d_in[10];
  const float* bi    = (const float*)d_in[11];
  const float* we1   = (const float*)d_in[12];
  const float* be1   = (const float*)d_in[13];
  const float* we2   = (const float*)d_in[14];
  const float* be2   = (const float*)d_in[15];
  const float* we3   = (const float*)d_in[16];
  const float* be3   = (const float*)d_in[17];
  const float* wp1   = (const float*)d_in[18];
  const float* bp1   = (const float*)d_in[19];
  const float* wp2   = (const float*)d_in[20];
  const float* bp2   = (const float*)d_in[21];
  const float* rootw = (const float*)d_in[22];
  const float* rootb = (const float*)d_in[23];

  float* out0 = (float*)d_out;        // next_actions [200,4]  (agg accumulated here)
  float* out1 = out0 + 800;           // node_concepts_explicit[0] [200,4]
  float* out2 = out0 + 1600;          // edge_attributes[0] [39800,4]

  // ---- workspace layout ----
  unsigned short* us = (unsigned short*)d_ws;
  unsigned short* w1T  = us;                 // [512][2048]
  unsigned short* w2T  = us + 1048576;       // [256][512]
  unsigned short* w3T  = us + 1179648;       // [1024][256]
  unsigned short* WrT  = us + 1441792;       // [512][1024]
  unsigned short* we2T = us + 1966080;       // [64][256]
  unsigned short* roiB = us + 1982464;       // [208][2048]
  unsigned short* h1   = us + 2408448;       // [208][512]
  unsigned short* h2   = us + 2514944;       // [208][256]
  unsigned short* xB   = us + 2568192;       // [208][1024]
  float* fb   = (float*)(us + 2781184);
  float* Tm   = fb;                          // [208][512]
  float* Pm   = fb + 106496;                 // [200][256]
  float* Qm   = fb + 157696;                 // [200][256]
  float* Um   = fb + 208896;                 // [200][4]
  float* wp1T = fb + 209696;                 // float4[128]

  // prep: all transposes/conversions + P/Q (897 blocks)
  k_prep<<<897, 256, 0, stream>>>(w1, w2, w3, wp2, we2, bbox, dir, we1, be1, roi, wp1,
                                  w1T, w2T, w3T, WrT, we2T, roiB, Pm, Qm, wp1T);

  // node MLP chain (bf16 MFMA, bias/relu fused)
  gemm_mf<16, 1, 0, 1><<<dim3(13, 32), 256, 0, stream>>>(roiB, w1T, b1, h1, 512);
  gemm_mf<4, 1, 0, 1><<<dim3(13, 16), 256, 0, stream>>>(h1, w2T, b2, h2, 256);
  gemm_mf<2, 0, 0, 1><<<dim3(13, 64), 256, 0, stream>>>(h2, w3T, b3, xB, 1024);

  // per-node vectors: nce -> out1, U, agg-init -> out0
  k_nodevec<<<200, 256, 0, stream>>>(xB, wi, bi, rootw, rootb, bp2, out1, Um, out0);

  // T = x @ Wr  (f32 out)
  gemm_mf<8, 0, 1, 0><<<dim3(13, 32), 256, 0, stream>>>(xB, WrT, nullptr, Tm, 512);

  // fused edge pipeline (atomics straight into out0)
  k_edge<<<622, 256, 0, stream>>>(Pm, Qm, we2T, be2, we3, be3, wp1T, bp1, pri, Tm, Um, out0, out2);
}